// Round 11
// baseline (1012.106 us; speedup 1.0000x reference)
//
#include <hip/hip_runtime.h>
#include <math.h>

#define BB 4
#define NN 4096
#define DEGQ 16
#define DDIM 128
#define EDIM 256
#define EE (NN*DEGQ)   // 65536
#define STR 68         // LDS row stride in floats (16B-aligned, padded)
#define STR4 17        // STR/4

// ws layout (in floats)
#define WS_XN     0
#define WS_UVPQ   (WS_XN + BB*NN*DDIM)            // per-node u,v,p,q: [B*N][768]
#define WS_SCORES (WS_UVPQ + (size_t)BB*NN*768)
#define WS_THR    (WS_SCORES + (size_t)BB*EE)     // 8 floats
#define WS_SELP   (WS_THR + 8)                    // 4 u32
#define WS_SELR   (WS_SELP + 4)                   // 4 i32
#define WS_GHIST  (WS_SELR + 4)                   // 1024 u32
#define WS_BN     (WS_GHIST + 1024)               // 768 floats

// ---------------- normalize: one wave per node row ----------------
__global__ void k_norm(const float* __restrict__ nf, float* __restrict__ xn) {
    int wave = (blockIdx.x * blockDim.x + threadIdx.x) >> 6;
    int lane = threadIdx.x & 63;
    if (wave >= BB * NN) return;
    const float* row = nf + (size_t)wave * DDIM;
    float2 v = *(const float2*)(row + 2 * lane);
    float ss = v.x * v.x + v.y * v.y;
#pragma unroll
    for (int d = 32; d; d >>= 1) ss += __shfl_xor(ss, d, 64);
    float n = fmaxf(sqrtf(ss), 1e-12f);
    float inv = 1.0f / n;
    float2 o; o.x = v.x * inv; o.y = v.y * inv;
    *(float2*)(xn + (size_t)wave * DDIM + 2 * lane) = o;
}

// ---------------- BN constants + select-state init ----------------
__global__ void k_prep(const float* g1, const float* be1, const float* m1, const float* v1,
                       const float* g2, const float* be2, const float* m2, const float* v2,
                       float* bn, unsigned* ghist, unsigned* selp, int* selr) {
    int c = threadIdx.x;
    ghist[c] = 0u; ghist[256 + c] = 0u; ghist[512 + c] = 0u; ghist[768 + c] = 0u;
    if (c < 4) { selp[c] = 0u; selr[c] = EE / 2 - 1; }
    if (c < 256) {
        float s = g1[c] / sqrtf(v1[c] + 1e-5f);
        bn[c] = s; bn[256 + c] = be1[c] - m1[c] * s;
    }
    if (c < 128) {
        float s = g2[c] / sqrtf(v2[c] + 1e-5f);
        bn[512 + c] = s; bn[640 + c] = be2[c] - m2[c] * s;
    }
}

// ---------------- per-node u,v,p,q = xn @ {Wa1_top, Wa1_bot, W1a, W1b} ----------------
__global__ void k_uvpq(const float* __restrict__ xn, const float* __restrict__ Wa1,
                       const float* __restrict__ W1, float* __restrict__ uvpq) {
    int chunk = blockIdx.y;
    const float* wbase; int wstride; int ocol;
    switch (chunk) {
        case 0: wbase = Wa1;                 wstride = 128; ocol = 0;   break;
        case 1: wbase = Wa1 + 128 * 128;     wstride = 128; ocol = 128; break;
        case 2: wbase = W1;                  wstride = 256; ocol = 256; break;
        case 3: wbase = W1 + 128;            wstride = 256; ocol = 384; break;
        case 4: wbase = W1 + 128 * 256;      wstride = 256; ocol = 512; break;
        default: wbase = W1 + 128 * 256 + 128; wstride = 256; ocol = 640; break;
    }
    int wv = threadIdx.x >> 6, lane = threadIdx.x & 63;
    int nodebase = blockIdx.x * 32 + wv * 8;
    const float* xrow[8];
#pragma unroll
    for (int j = 0; j < 8; ++j) xrow[j] = xn + (size_t)(nodebase + j) * DDIM;
    float acc0[8] = {}, acc1[8] = {};
#pragma unroll 4
    for (int k = 0; k < 128; ++k) {
        float w0 = wbase[k * wstride + lane];
        float w1 = wbase[k * wstride + 64 + lane];
#pragma unroll
        for (int j = 0; j < 8; ++j) {
            float a = xrow[j][k];
            acc0[j] = fmaf(a, w0, acc0[j]);
            acc1[j] = fmaf(a, w1, acc1[j]);
        }
    }
#pragma unroll
    for (int j = 0; j < 8; ++j) {
        float* orow = uvpq + (size_t)(nodebase + j) * 768 + ocol;
        orow[lane] = acc0[j];
        orow[64 + lane] = acc1[j];
    }
}

// ---------------- fused edge pipeline: zero-barrier, 128-row LDS pool, low-VGPR ------
// Per-wave slice: rows 0..127 x its 8 edge-cols. Dataflow chain (no barriers):
// h1 -> g -> (GEMV2-HI: h2hi in 16 regs) -> (GEMV2-LO: h2_lo overlays g) ->
// GEMV3 half1 -> h2hi overlays h2_lo -> half2. Peak live regs ~50 -> fits the
// 64-VGPR occupancy step: 8 waves/SIMD x 4 blocks/CU (LDS 35.3KB).
__global__ __launch_bounds__(512, 8) void
k_edge(const float* __restrict__ xn, const float* __restrict__ uvpq,
       const float* __restrict__ Wa2, const float* __restrict__ ba1,
       const float* __restrict__ ba2, const float* __restrict__ W1,
       const float* __restrict__ b1, const float* __restrict__ W2,
       const float* __restrict__ b2, const float* __restrict__ W3,
       const float* __restrict__ b3, const int* __restrict__ src,
       const int* __restrict__ tgt, const float* __restrict__ bn,
       float* __restrict__ scores) {
    __shared__ float smem[128 * STR];
    __shared__ int ssrc[64], stgt[64];
    int tid = threadIdx.x;
    int b = blockIdx.y;
    int T0 = blockIdx.x * 64;
    int wv = tid >> 6, lane = tid & 63;
    int ebase = 8 * wv;
    if (lane < 8) {   // wave-private slice of the index arrays
        ssrc[ebase + lane] = src[(size_t)b * EE + T0 + ebase + lane];
        stgt[ebase + lane] = tgt[(size_t)b * EE + T0 + ebase + lane];
    }

    const float* uv = uvpq + (size_t)b * NN * 768;
    const float* xb = xn + (size_t)b * NN * DDIM;
    const float4* A4 = (const float4*)smem;

    // ---- h1 stage: per-wave, 8 edges, coalesced row reads; rows 0..127
    {
        float ba1a = ba1[lane], ba1b = ba1[64 + lane];
#pragma unroll
        for (int j = 0; j < 8; ++j) {
            int e = ebase + j;
            const float* ur = uv + (size_t)ssrc[e] * 768;
            const float* vr = uv + (size_t)stgt[e] * 768 + 128;
            smem[lane * STR + e] = fmaxf(ur[lane] + vr[lane] + ba1a, 0.0f);
            smem[(64 + lane) * STR + e] = fmaxf(ur[64 + lane] + vr[64 + lane] + ba1b, 0.0f);
        }
    }

    // ---- GEMV1: a = h1 @ Wa2 (+ba2), softmax over 128, g -> rows 0..127 (overlay h1)
    {
        float acc0[8] = {}, acc1[8] = {};
        const float* wa = Wa2 + lane;
#pragma unroll 4
        for (int k = 0; k < 128; ++k) {
            float w0 = wa[k * 128];
            float w1 = wa[k * 128 + 64];
            float4 hA = A4[k * STR4 + 2 * wv];
            float4 hB = A4[k * STR4 + 2 * wv + 1];
            acc0[0] = fmaf(hA.x, w0, acc0[0]); acc1[0] = fmaf(hA.x, w1, acc1[0]);
            acc0[1] = fmaf(hA.y, w0, acc0[1]); acc1[1] = fmaf(hA.y, w1, acc1[1]);
            acc0[2] = fmaf(hA.z, w0, acc0[2]); acc1[2] = fmaf(hA.z, w1, acc1[2]);
            acc0[3] = fmaf(hA.w, w0, acc0[3]); acc1[3] = fmaf(hA.w, w1, acc1[3]);
            acc0[4] = fmaf(hB.x, w0, acc0[4]); acc1[4] = fmaf(hB.x, w1, acc1[4]);
            acc0[5] = fmaf(hB.y, w0, acc0[5]); acc1[5] = fmaf(hB.y, w1, acc1[5]);
            acc0[6] = fmaf(hB.z, w0, acc0[6]); acc1[6] = fmaf(hB.z, w1, acc1[6]);
            acc0[7] = fmaf(hB.w, w0, acc0[7]); acc1[7] = fmaf(hB.w, w1, acc1[7]);
        }
        float bb0 = ba2[lane], bb1 = ba2[64 + lane];
#pragma unroll
        for (int j = 0; j < 8; ++j) {
            float a0 = acc0[j] + bb0, a1 = acc1[j] + bb1;
            float m = fmaxf(a0, a1);
#pragma unroll
            for (int d = 32; d; d >>= 1) m = fmaxf(m, __shfl_xor(m, d, 64));
            float p0 = expf(a0 - m), p1 = expf(a1 - m);
            float s = p0 + p1;
#pragma unroll
            for (int d = 32; d; d >>= 1) s += __shfl_xor(s, d, 64);
            float inv = 1.0f / s;
            int e = ebase + j;
            const float* xs = xb + (size_t)ssrc[e] * DDIM;
            const float* xt = xb + (size_t)stgt[e] * DDIM;
            float d0 = fabsf(xs[lane] - xt[lane]);
            float d1 = fabsf(xs[64 + lane] - xt[64 + lane]);
            smem[lane * STR + e] = d0 * p0 * inv;            // overlay h1 (consumed)
            smem[(64 + lane) * STR + e] = d1 * p1 * inv;
        }
    }

    // ---- GEMV2 pass HI: cols {128+lane, 192+lane}; h2hi kept in 16 regs
    float h2hi0[8], h2hi1[8];
    {
        float a2[8] = {}, a3[8] = {};
        const float* wc = W1 + 256 * 256 + lane;
#pragma unroll 2
        for (int k = 0; k < 128; ++k) {
            float w2 = wc[k * 256 + 128];
            float w3 = wc[k * 256 + 192];
            float4 gA = A4[k * STR4 + 2 * wv];
            float4 gB = A4[k * STR4 + 2 * wv + 1];
            a2[0] = fmaf(gA.x, w2, a2[0]); a3[0] = fmaf(gA.x, w3, a3[0]);
            a2[1] = fmaf(gA.y, w2, a2[1]); a3[1] = fmaf(gA.y, w3, a3[1]);
            a2[2] = fmaf(gA.z, w2, a2[2]); a3[2] = fmaf(gA.z, w3, a3[2]);
            a2[3] = fmaf(gA.w, w2, a2[3]); a3[3] = fmaf(gA.w, w3, a3[3]);
            a2[4] = fmaf(gB.x, w2, a2[4]); a3[4] = fmaf(gB.x, w3, a3[4]);
            a2[5] = fmaf(gB.y, w2, a2[5]); a3[5] = fmaf(gB.y, w3, a3[5]);
            a2[6] = fmaf(gB.z, w2, a2[6]); a3[6] = fmaf(gB.z, w3, a3[6]);
            a2[7] = fmaf(gB.w, w2, a2[7]); a3[7] = fmaf(gB.w, w3, a3[7]);
        }
        float s1c = bn[128 + lane], t1c = bn[256 + 128 + lane], b1c = b1[128 + lane];
        float s1d = bn[192 + lane], t1d = bn[256 + 192 + lane], b1d = b1[192 + lane];
#pragma unroll
        for (int j = 0; j < 8; ++j) {
            int e = ebase + j;
            const float* pr = uv + (size_t)ssrc[e] * 768 + 256;
            const float* qr = uv + (size_t)stgt[e] * 768 + 512;
            float y2 = a2[j] + pr[128 + lane] + qr[128 + lane] + b1c;
            float y3 = a3[j] + pr[192 + lane] + qr[192 + lane] + b1d;
            h2hi0[j] = fmaxf(fmaf(y2, s1c, t1c), 0.0f);
            h2hi1[j] = fmaxf(fmaf(y3, s1d, t1d), 0.0f);
        }
    }

    // ---- GEMV2 pass LO: cols {lane, 64+lane}; h2_lo -> LDS (overlay g, consumed)
    {
        float a0[8] = {}, a1[8] = {};
        const float* wc = W1 + 256 * 256 + lane;
#pragma unroll 2
        for (int k = 0; k < 128; ++k) {
            float w0 = wc[k * 256];
            float w1 = wc[k * 256 + 64];
            float4 gA = A4[k * STR4 + 2 * wv];
            float4 gB = A4[k * STR4 + 2 * wv + 1];
            a0[0] = fmaf(gA.x, w0, a0[0]); a1[0] = fmaf(gA.x, w1, a1[0]);
            a0[1] = fmaf(gA.y, w0, a0[1]); a1[1] = fmaf(gA.y, w1, a1[1]);
            a0[2] = fmaf(gA.z, w0, a0[2]); a1[2] = fmaf(gA.z, w1, a1[2]);
            a0[3] = fmaf(gA.w, w0, a0[3]); a1[3] = fmaf(gA.w, w1, a1[3]);
            a0[4] = fmaf(gB.x, w0, a0[4]); a1[4] = fmaf(gB.x, w1, a1[4]);
            a0[5] = fmaf(gB.y, w0, a0[5]); a1[5] = fmaf(gB.y, w1, a1[5]);
            a0[6] = fmaf(gB.z, w0, a0[6]); a1[6] = fmaf(gB.z, w1, a1[6]);
            a0[7] = fmaf(gB.w, w0, a0[7]); a1[7] = fmaf(gB.w, w1, a1[7]);
        }
        float s1a = bn[lane], t1a = bn[256 + lane], b1a = b1[lane];
        float s1b = bn[64 + lane], t1b = bn[256 + 64 + lane], b1b = b1[64 + lane];
#pragma unroll
        for (int j = 0; j < 8; ++j) {
            int e = ebase + j;
            const float* pr = uv + (size_t)ssrc[e] * 768 + 256;
            const float* qr = uv + (size_t)stgt[e] * 768 + 512;
            float y0 = a0[j] + pr[lane] + qr[lane] + b1a;
            float y1 = a1[j] + pr[64 + lane] + qr[64 + lane] + b1b;
            smem[lane * STR + e] = fmaxf(fmaf(y0, s1a, t1a), 0.0f);
            smem[(64 + lane) * STR + e] = fmaxf(fmaf(y1, s1b, t1b), 0.0f);
        }
    }

    // ---- GEMV3 half1: k=0..127 from LDS (h2_lo)
    float acc30[8] = {}, acc31[8] = {};
    {
        const float* w2p = W2 + lane;
#pragma unroll 4
        for (int k = 0; k < 128; ++k) {
            float w0 = w2p[k * 128];
            float w1 = w2p[k * 128 + 64];
            float4 hA = A4[k * STR4 + 2 * wv];
            float4 hB = A4[k * STR4 + 2 * wv + 1];
            acc30[0] = fmaf(hA.x, w0, acc30[0]); acc31[0] = fmaf(hA.x, w1, acc31[0]);
            acc30[1] = fmaf(hA.y, w0, acc30[1]); acc31[1] = fmaf(hA.y, w1, acc31[1]);
            acc30[2] = fmaf(hA.z, w0, acc30[2]); acc31[2] = fmaf(hA.z, w1, acc31[2]);
            acc30[3] = fmaf(hA.w, w0, acc30[3]); acc31[3] = fmaf(hA.w, w1, acc31[3]);
            acc30[4] = fmaf(hB.x, w0, acc30[4]); acc31[4] = fmaf(hB.x, w1, acc31[4]);
            acc30[5] = fmaf(hB.y, w0, acc30[5]); acc31[5] = fmaf(hB.y, w1, acc31[5]);
            acc30[6] = fmaf(hB.z, w0, acc30[6]); acc31[6] = fmaf(hB.z, w1, acc31[6]);
            acc30[7] = fmaf(hB.w, w0, acc30[7]); acc31[7] = fmaf(hB.w, w1, acc31[7]);
        }
    }
    // ---- overlay h2_hi into rows 0..127 (h2_lo fully consumed by half1)
#pragma unroll
    for (int j = 0; j < 8; ++j) {
        int e = ebase + j;
        smem[lane * STR + e] = h2hi0[j];            // row l    <-> k=128+l
        smem[(64 + lane) * STR + e] = h2hi1[j];     // row 64+l <-> k=192+l
    }
    // ---- GEMV3 half2: k=128..255 from overlaid rows
    {
        const float* w2p = W2 + lane;
#pragma unroll 4
        for (int k = 0; k < 128; ++k) {
            float w0 = w2p[(128 + k) * 128];
            float w1 = w2p[(128 + k) * 128 + 64];
            float4 hA = A4[k * STR4 + 2 * wv];
            float4 hB = A4[k * STR4 + 2 * wv + 1];
            acc30[0] = fmaf(hA.x, w0, acc30[0]); acc31[0] = fmaf(hA.x, w1, acc31[0]);
            acc30[1] = fmaf(hA.y, w0, acc30[1]); acc31[1] = fmaf(hA.y, w1, acc31[1]);
            acc30[2] = fmaf(hA.z, w0, acc30[2]); acc31[2] = fmaf(hA.z, w1, acc31[2]);
            acc30[3] = fmaf(hA.w, w0, acc30[3]); acc31[3] = fmaf(hA.w, w1, acc31[3]);
            acc30[4] = fmaf(hB.x, w0, acc30[4]); acc31[4] = fmaf(hB.x, w1, acc31[4]);
            acc30[5] = fmaf(hB.y, w0, acc30[5]); acc31[5] = fmaf(hB.y, w1, acc31[5]);
            acc30[6] = fmaf(hB.z, w0, acc30[6]); acc31[6] = fmaf(hB.z, w1, acc31[6]);
            acc30[7] = fmaf(hB.w, w0, acc30[7]); acc31[7] = fmaf(hB.w, w1, acc31[7]);
        }
    }
    // ---- BN2 + relu + logit + sigmoid
    {
        float s2a = bn[512 + lane], t2a = bn[640 + lane];
        float s2b = bn[512 + 64 + lane], t2b = bn[640 + 64 + lane];
        float b2a = b2[lane], b2b = b2[64 + lane];
        float w3a = W3[lane], w3b = W3[64 + lane];
        float b3v = b3[0];
#pragma unroll
        for (int j = 0; j < 8; ++j) {
            float h0 = fmaxf(fmaf(acc30[j] + b2a, s2a, t2a), 0.0f);
            float h1 = fmaxf(fmaf(acc31[j] + b2b, s2b, t2b), 0.0f);
            float lp = h0 * w3a + h1 * w3b;
#pragma unroll
            for (int d = 32; d; d >>= 1) lp += __shfl_xor(lp, d, 64);
            float sc = 1.0f / (1.0f + expf(-(lp + b3v)));
            if (lane == j) scores[(size_t)b * EE + T0 + ebase + j] = sc;
        }
    }
}

// ---------------- parallel radix-select: histogram pass ----------------
__global__ void k_hist(const float* __restrict__ scores, const unsigned* __restrict__ selp,
                       unsigned* __restrict__ ghist, int pass) {
    __shared__ unsigned h[256];
    int b = blockIdx.y;
    h[threadIdx.x] = 0u;
    __syncthreads();
    unsigned pref = selp[b];
    unsigned mask = (pass == 3) ? 0u : (0xFFFFFFFFu << ((pass + 1) * 8));
    const unsigned* sb = (const unsigned*)(scores + (size_t)b * EE);
    int base = blockIdx.x * 2048;
    for (int i = base + threadIdx.x; i < base + 2048; i += 256) {
        unsigned u = sb[i];
        if ((u & mask) == pref) atomicAdd(&h[(u >> (pass * 8)) & 255], 1u);
    }
    __syncthreads();
    unsigned v = h[threadIdx.x];
    if (v) atomicAdd(&ghist[b * 256 + threadIdx.x], v);
}

// ---------------- parallel radix-select: pick digit, reset hist ----------------
__global__ void k_pick(unsigned* __restrict__ ghist, unsigned* __restrict__ selp,
                       int* __restrict__ selr, float* __restrict__ thr, int pass) {
    __shared__ unsigned sh[256];
    int b = blockIdx.x;
    unsigned* gh = ghist + b * 256;
    sh[threadIdx.x] = gh[threadIdx.x];
    __syncthreads();
    if (threadIdx.x == 0) {
        unsigned r = (unsigned)selr[b], cum = 0;
        for (int x = 0; x < 256; ++x) {
            unsigned c = sh[x];
            if (cum + c > r) {
                selp[b] |= (unsigned)x << (pass * 8);
                selr[b] = (int)(r - cum);
                break;
            }
            cum += c;
        }
        if (pass == 0) thr[b] = __uint_as_float(selp[b]);
    }
    __syncthreads();
    gh[threadIdx.x] = 0u;
}

// ---------------- threshold + per-group repair + scatter ----------------
__global__ void k_scatter(const float* __restrict__ scores, const float* __restrict__ thr,
                          const int* __restrict__ src, const int* __restrict__ tgt,
                          const int* __restrict__ mep, float* __restrict__ out) {
    int gid = blockIdx.x * 256 + threadIdx.x;
    int b = gid >> 16;
    int lane = threadIdx.x & 63;
    int j = lane & 15;
    float s = scores[gid];
    float t = thr[b];
    bool above = (s >= t);
    unsigned long long bal = __ballot(above);
    int sub = lane >> 4;
    unsigned int mask16 = (unsigned int)((bal >> (sub * 16)) & 0xFFFFull);
    int active = __popc(mask16);
    int rank = 0;
#pragma unroll
    for (int j2 = 0; j2 < 16; ++j2) {
        float sv = __shfl(s, (lane & 48) + j2, 64);
        rank += (sv > s || (sv == s && j2 < j)) ? 1 : 0;
    }
    int me = *mep;
    int need = (active < me) ? min(me - active, DEGQ) : 0;
    bool keep = above || (rank < need);
    float wgt = keep ? s : 0.0f;
    out[(size_t)b * NN * NN + (size_t)src[gid] * NN + tgt[gid]] = wgt;
}

extern "C" void kernel_launch(void* const* d_in, const int* in_sizes, int n_in,
                              void* d_out, int out_size, void* d_ws, size_t ws_size,
                              hipStream_t stream) {
    const float* nf  = (const float*)d_in[0];
    const int*   src = (const int*)d_in[1];
    const int*   tgt = (const int*)d_in[2];
    const float* Wa1 = (const float*)d_in[3];
    const float* ba1 = (const float*)d_in[4];
    const float* Wa2 = (const float*)d_in[5];
    const float* ba2 = (const float*)d_in[6];
    const float* W1  = (const float*)d_in[7];
    const float* b1  = (const float*)d_in[8];
    const float* g1  = (const float*)d_in[9];
    const float* be1 = (const float*)d_in[10];
    const float* m1  = (const float*)d_in[11];
    const float* v1  = (const float*)d_in[12];
    const float* W2  = (const float*)d_in[13];
    const float* b2  = (const float*)d_in[14];
    const float* g2  = (const float*)d_in[15];
    const float* be2 = (const float*)d_in[16];
    const float* m2  = (const float*)d_in[17];
    const float* v2  = (const float*)d_in[18];
    const float* W3  = (const float*)d_in[19];
    const float* b3  = (const float*)d_in[20];
    const int*   mep = (const int*)d_in[21];

    float* ws = (float*)d_ws;
    float*    xn     = ws + WS_XN;
    float*    uvpq   = ws + WS_UVPQ;
    float*    scores = ws + WS_SCORES;
    float*    thrb   = ws + WS_THR;
    unsigned* selp   = (unsigned*)(ws + WS_SELP);
    int*      selr   = (int*)(ws + WS_SELR);
    unsigned* ghist  = (unsigned*)(ws + WS_GHIST);
    float*    bn     = ws + WS_BN;
    float*    out    = (float*)d_out;

    hipMemsetAsync(d_out, 0, (size_t)out_size * sizeof(float), stream);
    k_prep<<<1, 256, 0, stream>>>(g1, be1, m1, v1, g2, be2, m2, v2, bn, ghist, selp, selr);
    k_norm<<<(BB * NN) / 4, 256, 0, stream>>>(nf, xn);
    k_uvpq<<<dim3((BB * NN) / 32, 6), 256, 0, stream>>>(xn, Wa1, W1, uvpq);
    k_edge<<<dim3(EE / 64, BB), 512, 0, stream>>>(xn, uvpq, Wa2, ba1, ba2, W1, b1,
                                                  W2, b2, W3, b3, src, tgt, bn, scores);
    for (int pass = 3; pass >= 0; --pass) {
        k_hist<<<dim3(32, BB), 256, 0, stream>>>(scores, selp, ghist, pass);
        k_pick<<<BB, 256, 0, stream>>>(ghist, selp, selr, thrb, pass);
    }
    k_scatter<<<(BB * EE) / 256, 256, 0, stream>>>(scores, thrb, src, tgt, mep, out);
}

// Round 12
// 961.149 us; speedup vs baseline: 1.0530x; 1.0530x over previous
//
#include <hip/hip_runtime.h>
#include <math.h>

#define BB 4
#define NN 4096
#define DEGQ 16
#define DDIM 128
#define EDIM 256
#define EE (NN*DEGQ)   // 65536
#define STR 68         // LDS row stride in floats (16B-aligned, padded)
#define STR4 17        // STR/4

// ws layout (in floats)
#define WS_XN     0
#define WS_UVPQ   (WS_XN + BB*NN*DDIM)            // per-node u,v,p,q: [B*N][768]
#define WS_SCORES (WS_UVPQ + (size_t)BB*NN*768)
#define WS_THR    (WS_SCORES + (size_t)BB*EE)     // 8 floats
#define WS_SELP   (WS_THR + 8)                    // 4 u32
#define WS_SELR   (WS_SELP + 4)                   // 4 i32
#define WS_GHIST  (WS_SELR + 4)                   // 1024 u32
#define WS_BN     (WS_GHIST + 1024)               // 768 floats

// ---------------- normalize: one wave per node row ----------------
__global__ void k_norm(const float* __restrict__ nf, float* __restrict__ xn) {
    int wave = (blockIdx.x * blockDim.x + threadIdx.x) >> 6;
    int lane = threadIdx.x & 63;
    if (wave >= BB * NN) return;
    const float* row = nf + (size_t)wave * DDIM;
    float2 v = *(const float2*)(row + 2 * lane);
    float ss = v.x * v.x + v.y * v.y;
#pragma unroll
    for (int d = 32; d; d >>= 1) ss += __shfl_xor(ss, d, 64);
    float n = fmaxf(sqrtf(ss), 1e-12f);
    float inv = 1.0f / n;
    float2 o; o.x = v.x * inv; o.y = v.y * inv;
    *(float2*)(xn + (size_t)wave * DDIM + 2 * lane) = o;
}

// ---------------- BN constants + select-state init ----------------
__global__ void k_prep(const float* g1, const float* be1, const float* m1, const float* v1,
                       const float* g2, const float* be2, const float* m2, const float* v2,
                       float* bn, unsigned* ghist, unsigned* selp, int* selr) {
    int c = threadIdx.x;
    ghist[c] = 0u; ghist[256 + c] = 0u; ghist[512 + c] = 0u; ghist[768 + c] = 0u;
    if (c < 4) { selp[c] = 0u; selr[c] = EE / 2 - 1; }
    if (c < 256) {
        float s = g1[c] / sqrtf(v1[c] + 1e-5f);
        bn[c] = s; bn[256 + c] = be1[c] - m1[c] * s;
    }
    if (c < 128) {
        float s = g2[c] / sqrtf(v2[c] + 1e-5f);
        bn[512 + c] = s; bn[640 + c] = be2[c] - m2[c] * s;
    }
}

// ---------------- per-node u,v,p,q = xn @ {Wa1_top, Wa1_bot, W1a, W1b} ----------------
__global__ void k_uvpq(const float* __restrict__ xn, const float* __restrict__ Wa1,
                       const float* __restrict__ W1, float* __restrict__ uvpq) {
    int chunk = blockIdx.y;
    const float* wbase; int wstride; int ocol;
    switch (chunk) {
        case 0: wbase = Wa1;                 wstride = 128; ocol = 0;   break;
        case 1: wbase = Wa1 + 128 * 128;     wstride = 128; ocol = 128; break;
        case 2: wbase = W1;                  wstride = 256; ocol = 256; break;
        case 3: wbase = W1 + 128;            wstride = 256; ocol = 384; break;
        case 4: wbase = W1 + 128 * 256;      wstride = 256; ocol = 512; break;
        default: wbase = W1 + 128 * 256 + 128; wstride = 256; ocol = 640; break;
    }
    int wv = threadIdx.x >> 6, lane = threadIdx.x & 63;
    int nodebase = blockIdx.x * 32 + wv * 8;
    const float* xrow[8];
#pragma unroll
    for (int j = 0; j < 8; ++j) xrow[j] = xn + (size_t)(nodebase + j) * DDIM;
    float acc0[8] = {}, acc1[8] = {};
#pragma unroll 4
    for (int k = 0; k < 128; ++k) {
        float w0 = wbase[k * wstride + lane];
        float w1 = wbase[k * wstride + 64 + lane];
#pragma unroll
        for (int j = 0; j < 8; ++j) {
            float a = xrow[j][k];
            acc0[j] = fmaf(a, w0, acc0[j]);
            acc1[j] = fmaf(a, w1, acc1[j]);
        }
    }
#pragma unroll
    for (int j = 0; j < 8; ++j) {
        float* orow = uvpq + (size_t)(nodebase + j) * 768 + ocol;
        orow[lane] = acc0[j];
        orow[64 + lane] = acc1[j];
    }
}

// ---------------- fused edge pipeline: zero-barrier, 128-row LDS pool, low-VGPR ------
// Per-wave slice: rows 0..127 x its 8 edge-cols. Dataflow chain (no barriers):
// h1 -> g -> (GEMV2-HI: h2hi in 16 regs) -> (GEMV2-LO: h2_lo overlays g) ->
// GEMV3 half1 -> h2hi overlays h2_lo -> half2.
// launch_bounds(512,4): R8's identical mix compiled to 52 VGPR under this bound;
// split GEMV2 has lower peak pressure, so expect <=64 naturally (no spill).
// VGPR<=64 allows 8 waves/SIMD; LDS 35.3KB allows 4 blocks/CU -> 32 waves/CU.
__global__ __launch_bounds__(512, 4) void
k_edge(const float* __restrict__ xn, const float* __restrict__ uvpq,
       const float* __restrict__ Wa2, const float* __restrict__ ba1,
       const float* __restrict__ ba2, const float* __restrict__ W1,
       const float* __restrict__ b1, const float* __restrict__ W2,
       const float* __restrict__ b2, const float* __restrict__ W3,
       const float* __restrict__ b3, const int* __restrict__ src,
       const int* __restrict__ tgt, const float* __restrict__ bn,
       float* __restrict__ scores) {
    __shared__ float smem[128 * STR];
    __shared__ int ssrc[64], stgt[64];
    int tid = threadIdx.x;
    int b = blockIdx.y;
    int T0 = blockIdx.x * 64;
    int wv = tid >> 6, lane = tid & 63;
    int ebase = 8 * wv;
    if (lane < 8) {   // wave-private slice of the index arrays
        ssrc[ebase + lane] = src[(size_t)b * EE + T0 + ebase + lane];
        stgt[ebase + lane] = tgt[(size_t)b * EE + T0 + ebase + lane];
    }

    const float* uv = uvpq + (size_t)b * NN * 768;
    const float* xb = xn + (size_t)b * NN * DDIM;
    const float4* A4 = (const float4*)smem;

    // ---- h1 stage: per-wave, 8 edges, coalesced row reads; rows 0..127
    {
        float ba1a = ba1[lane], ba1b = ba1[64 + lane];
#pragma unroll
        for (int j = 0; j < 8; ++j) {
            int e = ebase + j;
            const float* ur = uv + (size_t)ssrc[e] * 768;
            const float* vr = uv + (size_t)stgt[e] * 768 + 128;
            smem[lane * STR + e] = fmaxf(ur[lane] + vr[lane] + ba1a, 0.0f);
            smem[(64 + lane) * STR + e] = fmaxf(ur[64 + lane] + vr[64 + lane] + ba1b, 0.0f);
        }
    }

    // ---- GEMV1: a = h1 @ Wa2 (+ba2), softmax over 128, g -> rows 0..127 (overlay h1)
    {
        float acc0[8] = {}, acc1[8] = {};
        const float* wa = Wa2 + lane;
#pragma unroll 4
        for (int k = 0; k < 128; ++k) {
            float w0 = wa[k * 128];
            float w1 = wa[k * 128 + 64];
            float4 hA = A4[k * STR4 + 2 * wv];
            float4 hB = A4[k * STR4 + 2 * wv + 1];
            acc0[0] = fmaf(hA.x, w0, acc0[0]); acc1[0] = fmaf(hA.x, w1, acc1[0]);
            acc0[1] = fmaf(hA.y, w0, acc0[1]); acc1[1] = fmaf(hA.y, w1, acc1[1]);
            acc0[2] = fmaf(hA.z, w0, acc0[2]); acc1[2] = fmaf(hA.z, w1, acc1[2]);
            acc0[3] = fmaf(hA.w, w0, acc0[3]); acc1[3] = fmaf(hA.w, w1, acc1[3]);
            acc0[4] = fmaf(hB.x, w0, acc0[4]); acc1[4] = fmaf(hB.x, w1, acc1[4]);
            acc0[5] = fmaf(hB.y, w0, acc0[5]); acc1[5] = fmaf(hB.y, w1, acc1[5]);
            acc0[6] = fmaf(hB.z, w0, acc0[6]); acc1[6] = fmaf(hB.z, w1, acc1[6]);
            acc0[7] = fmaf(hB.w, w0, acc0[7]); acc1[7] = fmaf(hB.w, w1, acc1[7]);
        }
        float bb0 = ba2[lane], bb1 = ba2[64 + lane];
#pragma unroll
        for (int j = 0; j < 8; ++j) {
            float a0 = acc0[j] + bb0, a1 = acc1[j] + bb1;
            float m = fmaxf(a0, a1);
#pragma unroll
            for (int d = 32; d; d >>= 1) m = fmaxf(m, __shfl_xor(m, d, 64));
            float p0 = expf(a0 - m), p1 = expf(a1 - m);
            float s = p0 + p1;
#pragma unroll
            for (int d = 32; d; d >>= 1) s += __shfl_xor(s, d, 64);
            float inv = 1.0f / s;
            int e = ebase + j;
            const float* xs = xb + (size_t)ssrc[e] * DDIM;
            const float* xt = xb + (size_t)stgt[e] * DDIM;
            float d0 = fabsf(xs[lane] - xt[lane]);
            float d1 = fabsf(xs[64 + lane] - xt[64 + lane]);
            smem[lane * STR + e] = d0 * p0 * inv;            // overlay h1 (consumed)
            smem[(64 + lane) * STR + e] = d1 * p1 * inv;
        }
    }

    // ---- GEMV2 pass HI: cols {128+lane, 192+lane}; h2hi kept in 16 regs
    float h2hi0[8], h2hi1[8];
    {
        float a2[8] = {}, a3[8] = {};
        const float* wc = W1 + 256 * 256 + lane;
#pragma unroll 2
        for (int k = 0; k < 128; ++k) {
            float w2 = wc[k * 256 + 128];
            float w3 = wc[k * 256 + 192];
            float4 gA = A4[k * STR4 + 2 * wv];
            float4 gB = A4[k * STR4 + 2 * wv + 1];
            a2[0] = fmaf(gA.x, w2, a2[0]); a3[0] = fmaf(gA.x, w3, a3[0]);
            a2[1] = fmaf(gA.y, w2, a2[1]); a3[1] = fmaf(gA.y, w3, a3[1]);
            a2[2] = fmaf(gA.z, w2, a2[2]); a3[2] = fmaf(gA.z, w3, a3[2]);
            a2[3] = fmaf(gA.w, w2, a2[3]); a3[3] = fmaf(gA.w, w3, a3[3]);
            a2[4] = fmaf(gB.x, w2, a2[4]); a3[4] = fmaf(gB.x, w3, a3[4]);
            a2[5] = fmaf(gB.y, w2, a2[5]); a3[5] = fmaf(gB.y, w3, a3[5]);
            a2[6] = fmaf(gB.z, w2, a2[6]); a3[6] = fmaf(gB.z, w3, a3[6]);
            a2[7] = fmaf(gB.w, w2, a2[7]); a3[7] = fmaf(gB.w, w3, a3[7]);
        }
        float s1c = bn[128 + lane], t1c = bn[256 + 128 + lane], b1c = b1[128 + lane];
        float s1d = bn[192 + lane], t1d = bn[256 + 192 + lane], b1d = b1[192 + lane];
#pragma unroll
        for (int j = 0; j < 8; ++j) {
            int e = ebase + j;
            const float* pr = uv + (size_t)ssrc[e] * 768 + 256;
            const float* qr = uv + (size_t)stgt[e] * 768 + 512;
            float y2 = a2[j] + pr[128 + lane] + qr[128 + lane] + b1c;
            float y3 = a3[j] + pr[192 + lane] + qr[192 + lane] + b1d;
            h2hi0[j] = fmaxf(fmaf(y2, s1c, t1c), 0.0f);
            h2hi1[j] = fmaxf(fmaf(y3, s1d, t1d), 0.0f);
        }
    }

    // ---- GEMV2 pass LO: cols {lane, 64+lane}; h2_lo -> LDS (overlay g, consumed)
    {
        float a0[8] = {}, a1[8] = {};
        const float* wc = W1 + 256 * 256 + lane;
#pragma unroll 2
        for (int k = 0; k < 128; ++k) {
            float w0 = wc[k * 256];
            float w1 = wc[k * 256 + 64];
            float4 gA = A4[k * STR4 + 2 * wv];
            float4 gB = A4[k * STR4 + 2 * wv + 1];
            a0[0] = fmaf(gA.x, w0, a0[0]); a1[0] = fmaf(gA.x, w1, a1[0]);
            a0[1] = fmaf(gA.y, w0, a0[1]); a1[1] = fmaf(gA.y, w1, a1[1]);
            a0[2] = fmaf(gA.z, w0, a0[2]); a1[2] = fmaf(gA.z, w1, a1[2]);
            a0[3] = fmaf(gA.w, w0, a0[3]); a1[3] = fmaf(gA.w, w1, a1[3]);
            a0[4] = fmaf(gB.x, w0, a0[4]); a1[4] = fmaf(gB.x, w1, a1[4]);
            a0[5] = fmaf(gB.y, w0, a0[5]); a1[5] = fmaf(gB.y, w1, a1[5]);
            a0[6] = fmaf(gB.z, w0, a0[6]); a1[6] = fmaf(gB.z, w1, a1[6]);
            a0[7] = fmaf(gB.w, w0, a0[7]); a1[7] = fmaf(gB.w, w1, a1[7]);
        }
        float s1a = bn[lane], t1a = bn[256 + lane], b1a = b1[lane];
        float s1b = bn[64 + lane], t1b = bn[256 + 64 + lane], b1b = b1[64 + lane];
#pragma unroll
        for (int j = 0; j < 8; ++j) {
            int e = ebase + j;
            const float* pr = uv + (size_t)ssrc[e] * 768 + 256;
            const float* qr = uv + (size_t)stgt[e] * 768 + 512;
            float y0 = a0[j] + pr[lane] + qr[lane] + b1a;
            float y1 = a1[j] + pr[64 + lane] + qr[64 + lane] + b1b;
            smem[lane * STR + e] = fmaxf(fmaf(y0, s1a, t1a), 0.0f);
            smem[(64 + lane) * STR + e] = fmaxf(fmaf(y1, s1b, t1b), 0.0f);
        }
    }

    // ---- GEMV3 half1: k=0..127 from LDS (h2_lo)
    float acc30[8] = {}, acc31[8] = {};
    {
        const float* w2p = W2 + lane;
#pragma unroll 4
        for (int k = 0; k < 128; ++k) {
            float w0 = w2p[k * 128];
            float w1 = w2p[k * 128 + 64];
            float4 hA = A4[k * STR4 + 2 * wv];
            float4 hB = A4[k * STR4 + 2 * wv + 1];
            acc30[0] = fmaf(hA.x, w0, acc30[0]); acc31[0] = fmaf(hA.x, w1, acc31[0]);
            acc30[1] = fmaf(hA.y, w0, acc30[1]); acc31[1] = fmaf(hA.y, w1, acc31[1]);
            acc30[2] = fmaf(hA.z, w0, acc30[2]); acc31[2] = fmaf(hA.z, w1, acc31[2]);
            acc30[3] = fmaf(hA.w, w0, acc30[3]); acc31[3] = fmaf(hA.w, w1, acc31[3]);
            acc30[4] = fmaf(hB.x, w0, acc30[4]); acc31[4] = fmaf(hB.x, w1, acc31[4]);
            acc30[5] = fmaf(hB.y, w0, acc30[5]); acc31[5] = fmaf(hB.y, w1, acc31[5]);
            acc30[6] = fmaf(hB.z, w0, acc30[6]); acc31[6] = fmaf(hB.z, w1, acc31[6]);
            acc30[7] = fmaf(hB.w, w0, acc30[7]); acc31[7] = fmaf(hB.w, w1, acc31[7]);
        }
    }
    // ---- overlay h2_hi into rows 0..127 (h2_lo fully consumed by half1)
#pragma unroll
    for (int j = 0; j < 8; ++j) {
        int e = ebase + j;
        smem[lane * STR + e] = h2hi0[j];            // row l    <-> k=128+l
        smem[(64 + lane) * STR + e] = h2hi1[j];     // row 64+l <-> k=192+l
    }
    // ---- GEMV3 half2: k=128..255 from overlaid rows
    {
        const float* w2p = W2 + lane;
#pragma unroll 4
        for (int k = 0; k < 128; ++k) {
            float w0 = w2p[(128 + k) * 128];
            float w1 = w2p[(128 + k) * 128 + 64];
            float4 hA = A4[k * STR4 + 2 * wv];
            float4 hB = A4[k * STR4 + 2 * wv + 1];
            acc30[0] = fmaf(hA.x, w0, acc30[0]); acc31[0] = fmaf(hA.x, w1, acc31[0]);
            acc30[1] = fmaf(hA.y, w0, acc30[1]); acc31[1] = fmaf(hA.y, w1, acc31[1]);
            acc30[2] = fmaf(hA.z, w0, acc30[2]); acc31[2] = fmaf(hA.z, w1, acc31[2]);
            acc30[3] = fmaf(hA.w, w0, acc30[3]); acc31[3] = fmaf(hA.w, w1, acc31[3]);
            acc30[4] = fmaf(hB.x, w0, acc30[4]); acc31[4] = fmaf(hB.x, w1, acc31[4]);
            acc30[5] = fmaf(hB.y, w0, acc30[5]); acc31[5] = fmaf(hB.y, w1, acc31[5]);
            acc30[6] = fmaf(hB.z, w0, acc30[6]); acc31[6] = fmaf(hB.z, w1, acc31[6]);
            acc30[7] = fmaf(hB.w, w0, acc30[7]); acc31[7] = fmaf(hB.w, w1, acc31[7]);
        }
    }
    // ---- BN2 + relu + logit + sigmoid
    {
        float s2a = bn[512 + lane], t2a = bn[640 + lane];
        float s2b = bn[512 + 64 + lane], t2b = bn[640 + 64 + lane];
        float b2a = b2[lane], b2b = b2[64 + lane];
        float w3a = W3[lane], w3b = W3[64 + lane];
        float b3v = b3[0];
#pragma unroll
        for (int j = 0; j < 8; ++j) {
            float h0 = fmaxf(fmaf(acc30[j] + b2a, s2a, t2a), 0.0f);
            float h1 = fmaxf(fmaf(acc31[j] + b2b, s2b, t2b), 0.0f);
            float lp = h0 * w3a + h1 * w3b;
#pragma unroll
            for (int d = 32; d; d >>= 1) lp += __shfl_xor(lp, d, 64);
            float sc = 1.0f / (1.0f + expf(-(lp + b3v)));
            if (lane == j) scores[(size_t)b * EE + T0 + ebase + j] = sc;
        }
    }
}

// ---------------- parallel radix-select: histogram pass ----------------
__global__ void k_hist(const float* __restrict__ scores, const unsigned* __restrict__ selp,
                       unsigned* __restrict__ ghist, int pass) {
    __shared__ unsigned h[256];
    int b = blockIdx.y;
    h[threadIdx.x] = 0u;
    __syncthreads();
    unsigned pref = selp[b];
    unsigned mask = (pass == 3) ? 0u : (0xFFFFFFFFu << ((pass + 1) * 8));
    const unsigned* sb = (const unsigned*)(scores + (size_t)b * EE);
    int base = blockIdx.x * 2048;
    for (int i = base + threadIdx.x; i < base + 2048; i += 256) {
        unsigned u = sb[i];
        if ((u & mask) == pref) atomicAdd(&h[(u >> (pass * 8)) & 255], 1u);
    }
    __syncthreads();
    unsigned v = h[threadIdx.x];
    if (v) atomicAdd(&ghist[b * 256 + threadIdx.x], v);
}

// ---------------- parallel radix-select: pick digit, reset hist ----------------
__global__ void k_pick(unsigned* __restrict__ ghist, unsigned* __restrict__ selp,
                       int* __restrict__ selr, float* __restrict__ thr, int pass) {
    __shared__ unsigned sh[256];
    int b = blockIdx.x;
    unsigned* gh = ghist + b * 256;
    sh[threadIdx.x] = gh[threadIdx.x];
    __syncthreads();
    if (threadIdx.x == 0) {
        unsigned r = (unsigned)selr[b], cum = 0;
        for (int x = 0; x < 256; ++x) {
            unsigned c = sh[x];
            if (cum + c > r) {
                selp[b] |= (unsigned)x << (pass * 8);
                selr[b] = (int)(r - cum);
                break;
            }
            cum += c;
        }
        if (pass == 0) thr[b] = __uint_as_float(selp[b]);
    }
    __syncthreads();
    gh[threadIdx.x] = 0u;
}

// ---------------- threshold + per-group repair + scatter ----------------
__global__ void k_scatter(const float* __restrict__ scores, const float* __restrict__ thr,
                          const int* __restrict__ src, const int* __restrict__ tgt,
                          const int* __restrict__ mep, float* __restrict__ out) {
    int gid = blockIdx.x * 256 + threadIdx.x;
    int b = gid >> 16;
    int lane = threadIdx.x & 63;
    int j = lane & 15;
    float s = scores[gid];
    float t = thr[b];
    bool above = (s >= t);
    unsigned long long bal = __ballot(above);
    int sub = lane >> 4;
    unsigned int mask16 = (unsigned int)((bal >> (sub * 16)) & 0xFFFFull);
    int active = __popc(mask16);
    int rank = 0;
#pragma unroll
    for (int j2 = 0; j2 < 16; ++j2) {
        float sv = __shfl(s, (lane & 48) + j2, 64);
        rank += (sv > s || (sv == s && j2 < j)) ? 1 : 0;
    }
    int me = *mep;
    int need = (active < me) ? min(me - active, DEGQ) : 0;
    bool keep = above || (rank < need);
    float wgt = keep ? s : 0.0f;
    out[(size_t)b * NN * NN + (size_t)src[gid] * NN + tgt[gid]] = wgt;
}

extern "C" void kernel_launch(void* const* d_in, const int* in_sizes, int n_in,
                              void* d_out, int out_size, void* d_ws, size_t ws_size,
                              hipStream_t stream) {
    const float* nf  = (const float*)d_in[0];
    const int*   src = (const int*)d_in[1];
    const int*   tgt = (const int*)d_in[2];
    const float* Wa1 = (const float*)d_in[3];
    const float* ba1 = (const float*)d_in[4];
    const float* Wa2 = (const float*)d_in[5];
    const float* ba2 = (const float*)d_in[6];
    const float* W1  = (const float*)d_in[7];
    const float* b1  = (const float*)d_in[8];
    const float* g1  = (const float*)d_in[9];
    const float* be1 = (const float*)d_in[10];
    const float* m1  = (const float*)d_in[11];
    const float* v1  = (const float*)d_in[12];
    const float* W2  = (const float*)d_in[13];
    const float* b2  = (const float*)d_in[14];
    const float* g2  = (const float*)d_in[15];
    const float* be2 = (const float*)d_in[16];
    const float* m2  = (const float*)d_in[17];
    const float* v2  = (const float*)d_in[18];
    const float* W3  = (const float*)d_in[19];
    const float* b3  = (const float*)d_in[20];
    const int*   mep = (const int*)d_in[21];

    float* ws = (float*)d_ws;
    float*    xn     = ws + WS_XN;
    float*    uvpq   = ws + WS_UVPQ;
    float*    scores = ws + WS_SCORES;
    float*    thrb   = ws + WS_THR;
    unsigned* selp   = (unsigned*)(ws + WS_SELP);
    int*      selr   = (int*)(ws + WS_SELR);
    unsigned* ghist  = (unsigned*)(ws + WS_GHIST);
    float*    bn     = ws + WS_BN;
    float*    out    = (float*)d_out;

    hipMemsetAsync(d_out, 0, (size_t)out_size * sizeof(float), stream);
    k_prep<<<1, 256, 0, stream>>>(g1, be1, m1, v1, g2, be2, m2, v2, bn, ghist, selp, selr);
    k_norm<<<(BB * NN) / 4, 256, 0, stream>>>(nf, xn);
    k_uvpq<<<dim3((BB * NN) / 32, 6), 256, 0, stream>>>(xn, Wa1, W1, uvpq);
    k_edge<<<dim3(EE / 64, BB), 512, 0, stream>>>(xn, uvpq, Wa2, ba1, ba2, W1, b1,
                                                  W2, b2, W3, b3, src, tgt, bn, scores);
    for (int pass = 3; pass >= 0; --pass) {
        k_hist<<<dim3(32, BB), 256, 0, stream>>>(scores, selp, ghist, pass);
        k_pick<<<BB, 256, 0, stream>>>(ghist, selp, selr, thrb, pass);
    }
    k_scatter<<<(BB * EE) / 256, 256, 0, stream>>>(scores, thrb, src, tgt, mep, out);
}

// Round 13
// 845.024 us; speedup vs baseline: 1.1977x; 1.1374x over previous
//
#include <hip/hip_runtime.h>
#include <math.h>

#define BB 4
#define NN 4096
#define DEGQ 16
#define DDIM 128
#define EDIM 256
#define EE (NN*DEGQ)   // 65536
#define STR 68         // LDS row stride in floats (16B-aligned, padded)
#define STR4 17        // STR/4

// ws layout (in floats)
#define WS_XN     0
#define WS_UVPQ   (WS_XN + BB*NN*DDIM)            // per-node u,v,p,q: [B*N][768]
#define WS_SCORES (WS_UVPQ + (size_t)BB*NN*768)
#define WS_THR    (WS_SCORES + (size_t)BB*EE)     // 8 floats
#define WS_SELP   (WS_THR + 8)                    // 4 u32
#define WS_SELR   (WS_SELP + 4)                   // 4 i32
#define WS_GHIST  (WS_SELR + 4)                   // 1024 u32
#define WS_BN     (WS_GHIST + 1024)               // 768 floats

// ---------------- normalize: one wave per node row ----------------
__global__ void k_norm(const float* __restrict__ nf, float* __restrict__ xn) {
    int wave = (blockIdx.x * blockDim.x + threadIdx.x) >> 6;
    int lane = threadIdx.x & 63;
    if (wave >= BB * NN) return;
    const float* row = nf + (size_t)wave * DDIM;
    float2 v = *(const float2*)(row + 2 * lane);
    float ss = v.x * v.x + v.y * v.y;
#pragma unroll
    for (int d = 32; d; d >>= 1) ss += __shfl_xor(ss, d, 64);
    float n = fmaxf(sqrtf(ss), 1e-12f);
    float inv = 1.0f / n;
    float2 o; o.x = v.x * inv; o.y = v.y * inv;
    *(float2*)(xn + (size_t)wave * DDIM + 2 * lane) = o;
}

// ---------------- BN constants + select-state init ----------------
__global__ void k_prep(const float* g1, const float* be1, const float* m1, const float* v1,
                       const float* g2, const float* be2, const float* m2, const float* v2,
                       float* bn, unsigned* ghist, unsigned* selp, int* selr) {
    int c = threadIdx.x;
    ghist[c] = 0u; ghist[256 + c] = 0u; ghist[512 + c] = 0u; ghist[768 + c] = 0u;
    if (c < 4) { selp[c] = 0u; selr[c] = EE / 2 - 1; }
    if (c < 256) {
        float s = g1[c] / sqrtf(v1[c] + 1e-5f);
        bn[c] = s; bn[256 + c] = be1[c] - m1[c] * s;
    }
    if (c < 128) {
        float s = g2[c] / sqrtf(v2[c] + 1e-5f);
        bn[512 + c] = s; bn[640 + c] = be2[c] - m2[c] * s;
    }
}

// ---------------- per-node u,v,p,q = xn @ {Wa1_top, Wa1_bot, W1a, W1b} ----------------
__global__ void k_uvpq(const float* __restrict__ xn, const float* __restrict__ Wa1,
                       const float* __restrict__ W1, float* __restrict__ uvpq) {
    int chunk = blockIdx.y;
    const float* wbase; int wstride; int ocol;
    switch (chunk) {
        case 0: wbase = Wa1;                 wstride = 128; ocol = 0;   break;
        case 1: wbase = Wa1 + 128 * 128;     wstride = 128; ocol = 128; break;
        case 2: wbase = W1;                  wstride = 256; ocol = 256; break;
        case 3: wbase = W1 + 128;            wstride = 256; ocol = 384; break;
        case 4: wbase = W1 + 128 * 256;      wstride = 256; ocol = 512; break;
        default: wbase = W1 + 128 * 256 + 128; wstride = 256; ocol = 640; break;
    }
    int wv = threadIdx.x >> 6, lane = threadIdx.x & 63;
    int nodebase = blockIdx.x * 32 + wv * 8;
    const float* xrow[8];
#pragma unroll
    for (int j = 0; j < 8; ++j) xrow[j] = xn + (size_t)(nodebase + j) * DDIM;
    float acc0[8] = {}, acc1[8] = {};
#pragma unroll 4
    for (int k = 0; k < 128; ++k) {
        float w0 = wbase[k * wstride + lane];
        float w1 = wbase[k * wstride + 64 + lane];
#pragma unroll
        for (int j = 0; j < 8; ++j) {
            float a = xrow[j][k];
            acc0[j] = fmaf(a, w0, acc0[j]);
            acc1[j] = fmaf(a, w1, acc1[j]);
        }
    }
#pragma unroll
    for (int j = 0; j < 8; ++j) {
        float* orow = uvpq + (size_t)(nodebase + j) * 768 + ocol;
        orow[lane] = acc0[j];
        orow[64 + lane] = acc1[j];
    }
}

// ---------------- fused edge pipeline: ZERO-BARRIER wave-private (R8) + setprio ------
// Each wave owns 8 edges end-to-end; no __syncthreads. Waves free-run at different
// phases -> s_setprio(1) around the FMA k-loops lets FMA-phase waves preempt
// gather/softmax-phase waves (T5 regime: independent wave streams, m191).
__global__ __launch_bounds__(512, 4) void
k_edge(const float* __restrict__ xn, const float* __restrict__ uvpq,
       const float* __restrict__ Wa2, const float* __restrict__ ba1,
       const float* __restrict__ ba2, const float* __restrict__ W1,
       const float* __restrict__ b1, const float* __restrict__ W2,
       const float* __restrict__ b2, const float* __restrict__ W3,
       const float* __restrict__ b3, const int* __restrict__ src,
       const int* __restrict__ tgt, const float* __restrict__ bn,
       float* __restrict__ scores) {
    __shared__ float smem[256 * STR];
    __shared__ int ssrc[64], stgt[64];
    int tid = threadIdx.x;
    int b = blockIdx.y;
    int T0 = blockIdx.x * 64;
    int wv = tid >> 6, lane = tid & 63;
    int ebase = 8 * wv;
    if (lane < 8) {   // wave-private slice of the index arrays
        ssrc[ebase + lane] = src[(size_t)b * EE + T0 + ebase + lane];
        stgt[ebase + lane] = tgt[(size_t)b * EE + T0 + ebase + lane];
    }

    const float* uv = uvpq + (size_t)b * NN * 768;
    const float* xb = xn + (size_t)b * NN * DDIM;
    const float4* A4 = (const float4*)smem;

    // ---- h1 stage: per-wave, 8 edges, coalesced row reads
    {
        float ba1a = ba1[lane], ba1b = ba1[64 + lane];
#pragma unroll
        for (int j = 0; j < 8; ++j) {
            int e = ebase + j;
            const float* ur = uv + (size_t)ssrc[e] * 768;
            const float* vr = uv + (size_t)stgt[e] * 768 + 128;
            smem[lane * STR + e] = fmaxf(ur[lane] + vr[lane] + ba1a, 0.0f);
            smem[(64 + lane) * STR + e] = fmaxf(ur[64 + lane] + vr[64 + lane] + ba1b, 0.0f);
        }
    }

    // ---- GEMV1: a = h1 @ Wa2 (+ba2), softmax over 128, gT[c][e] = |sf-tf|[c]*att[c]
    {
        float acc0[8] = {}, acc1[8] = {};
        const float* wa = Wa2 + lane;
        __builtin_amdgcn_s_setprio(1);
#pragma unroll 4
        for (int k = 0; k < 128; ++k) {
            float w0 = wa[k * 128];
            float w1 = wa[k * 128 + 64];
            float4 hA = A4[k * STR4 + 2 * wv];
            float4 hB = A4[k * STR4 + 2 * wv + 1];
            acc0[0] = fmaf(hA.x, w0, acc0[0]); acc1[0] = fmaf(hA.x, w1, acc1[0]);
            acc0[1] = fmaf(hA.y, w0, acc0[1]); acc1[1] = fmaf(hA.y, w1, acc1[1]);
            acc0[2] = fmaf(hA.z, w0, acc0[2]); acc1[2] = fmaf(hA.z, w1, acc1[2]);
            acc0[3] = fmaf(hA.w, w0, acc0[3]); acc1[3] = fmaf(hA.w, w1, acc1[3]);
            acc0[4] = fmaf(hB.x, w0, acc0[4]); acc1[4] = fmaf(hB.x, w1, acc1[4]);
            acc0[5] = fmaf(hB.y, w0, acc0[5]); acc1[5] = fmaf(hB.y, w1, acc1[5]);
            acc0[6] = fmaf(hB.z, w0, acc0[6]); acc1[6] = fmaf(hB.z, w1, acc1[6]);
            acc0[7] = fmaf(hB.w, w0, acc0[7]); acc1[7] = fmaf(hB.w, w1, acc1[7]);
        }
        __builtin_amdgcn_s_setprio(0);
        float bb0 = ba2[lane], bb1 = ba2[64 + lane];
#pragma unroll
        for (int j = 0; j < 8; ++j) {
            float a0 = acc0[j] + bb0, a1 = acc1[j] + bb1;
            float m = fmaxf(a0, a1);
#pragma unroll
            for (int d = 32; d; d >>= 1) m = fmaxf(m, __shfl_xor(m, d, 64));
            float p0 = expf(a0 - m), p1 = expf(a1 - m);
            float s = p0 + p1;
#pragma unroll
            for (int d = 32; d; d >>= 1) s += __shfl_xor(s, d, 64);
            float inv = 1.0f / s;
            int e = ebase + j;
            const float* xs = xb + (size_t)ssrc[e] * DDIM;
            const float* xt = xb + (size_t)stgt[e] * DDIM;
            float d0 = fabsf(xs[lane] - xt[lane]);
            float d1 = fabsf(xs[64 + lane] - xt[64 + lane]);
            smem[128 * STR + lane * STR + e] = d0 * p0 * inv;
            smem[128 * STR + (64 + lane) * STR + e] = d1 * p1 * inv;
        }
    }

    // ---- GEMV2: c = g @ W1c ; y = c + p_s + q_t + b1 ; h2 = relu(BN1)
    float acc2[8][4] = {};
    {
        const float* wc = W1 + 256 * 256 + lane;
        __builtin_amdgcn_s_setprio(1);
#pragma unroll 2
        for (int k = 0; k < 128; ++k) {
            float w0 = wc[k * 256];
            float w1 = wc[k * 256 + 64];
            float w2 = wc[k * 256 + 128];
            float w3 = wc[k * 256 + 192];
            float4 gA = A4[128 * STR4 + k * STR4 + 2 * wv];
            float4 gB = A4[128 * STR4 + k * STR4 + 2 * wv + 1];
            acc2[0][0] = fmaf(gA.x, w0, acc2[0][0]); acc2[0][1] = fmaf(gA.x, w1, acc2[0][1]);
            acc2[0][2] = fmaf(gA.x, w2, acc2[0][2]); acc2[0][3] = fmaf(gA.x, w3, acc2[0][3]);
            acc2[1][0] = fmaf(gA.y, w0, acc2[1][0]); acc2[1][1] = fmaf(gA.y, w1, acc2[1][1]);
            acc2[1][2] = fmaf(gA.y, w2, acc2[1][2]); acc2[1][3] = fmaf(gA.y, w3, acc2[1][3]);
            acc2[2][0] = fmaf(gA.z, w0, acc2[2][0]); acc2[2][1] = fmaf(gA.z, w1, acc2[2][1]);
            acc2[2][2] = fmaf(gA.z, w2, acc2[2][2]); acc2[2][3] = fmaf(gA.z, w3, acc2[2][3]);
            acc2[3][0] = fmaf(gA.w, w0, acc2[3][0]); acc2[3][1] = fmaf(gA.w, w1, acc2[3][1]);
            acc2[3][2] = fmaf(gA.w, w2, acc2[3][2]); acc2[3][3] = fmaf(gA.w, w3, acc2[3][3]);
            acc2[4][0] = fmaf(gB.x, w0, acc2[4][0]); acc2[4][1] = fmaf(gB.x, w1, acc2[4][1]);
            acc2[4][2] = fmaf(gB.x, w2, acc2[4][2]); acc2[4][3] = fmaf(gB.x, w3, acc2[4][3]);
            acc2[5][0] = fmaf(gB.y, w0, acc2[5][0]); acc2[5][1] = fmaf(gB.y, w1, acc2[5][1]);
            acc2[5][2] = fmaf(gB.y, w2, acc2[5][2]); acc2[5][3] = fmaf(gB.y, w3, acc2[5][3]);
            acc2[6][0] = fmaf(gB.z, w0, acc2[6][0]); acc2[6][1] = fmaf(gB.z, w1, acc2[6][1]);
            acc2[6][2] = fmaf(gB.z, w2, acc2[6][2]); acc2[6][3] = fmaf(gB.z, w3, acc2[6][3]);
            acc2[7][0] = fmaf(gB.w, w0, acc2[7][0]); acc2[7][1] = fmaf(gB.w, w1, acc2[7][1]);
            acc2[7][2] = fmaf(gB.w, w2, acc2[7][2]); acc2[7][3] = fmaf(gB.w, w3, acc2[7][3]);
        }
        __builtin_amdgcn_s_setprio(0);
    }
    {
        float s1v[4], t1v[4], b1v[4];
#pragma unroll
        for (int i = 0; i < 4; ++i) {
            int c = lane + 64 * i;
            s1v[i] = bn[c]; t1v[i] = bn[256 + c]; b1v[i] = b1[c];
        }
        // h2T write overlays h1 rows (dead) and this wave's own gT columns
        // (fully consumed by this wave's GEMV2 k-loop above) -> no barrier.
#pragma unroll
        for (int j = 0; j < 8; ++j) {
            int e = ebase + j;
            const float* pr = uv + (size_t)ssrc[e] * 768 + 256;
            const float* qr = uv + (size_t)stgt[e] * 768 + 512;
#pragma unroll
            for (int i = 0; i < 4; ++i) {
                int c = lane + 64 * i;
                float y = acc2[j][i] + pr[c] + qr[c] + b1v[i];
                smem[c * STR + e] = fmaxf(fmaf(y, s1v[i], t1v[i]), 0.0f);
            }
        }
    }

    // ---- GEMV3: h3 = relu(BN2(h2 @ W2 + b2)); logit = h3 @ W3 + b3; score = sigmoid
    {
        float acc30[8] = {}, acc31[8] = {};
        const float* w2p = W2 + lane;
        __builtin_amdgcn_s_setprio(1);
#pragma unroll 4
        for (int k = 0; k < 256; ++k) {
            float w0 = w2p[k * 128];
            float w1 = w2p[k * 128 + 64];
            float4 hA = A4[k * STR4 + 2 * wv];
            float4 hB = A4[k * STR4 + 2 * wv + 1];
            acc30[0] = fmaf(hA.x, w0, acc30[0]); acc31[0] = fmaf(hA.x, w1, acc31[0]);
            acc30[1] = fmaf(hA.y, w0, acc30[1]); acc31[1] = fmaf(hA.y, w1, acc31[1]);
            acc30[2] = fmaf(hA.z, w0, acc30[2]); acc31[2] = fmaf(hA.z, w1, acc31[2]);
            acc30[3] = fmaf(hA.w, w0, acc30[3]); acc31[3] = fmaf(hA.w, w1, acc31[3]);
            acc30[4] = fmaf(hB.x, w0, acc30[4]); acc31[4] = fmaf(hB.x, w1, acc31[4]);
            acc30[5] = fmaf(hB.y, w0, acc30[5]); acc31[5] = fmaf(hB.y, w1, acc31[5]);
            acc30[6] = fmaf(hB.z, w0, acc30[6]); acc31[6] = fmaf(hB.z, w1, acc31[6]);
            acc30[7] = fmaf(hB.w, w0, acc30[7]); acc31[7] = fmaf(hB.w, w1, acc31[7]);
        }
        __builtin_amdgcn_s_setprio(0);
        float s2a = bn[512 + lane], t2a = bn[640 + lane];
        float s2b = bn[512 + 64 + lane], t2b = bn[640 + 64 + lane];
        float b2a = b2[lane], b2b = b2[64 + lane];
        float w3a = W3[lane], w3b = W3[64 + lane];
        float b3v = b3[0];
#pragma unroll
        for (int j = 0; j < 8; ++j) {
            float h0 = fmaxf(fmaf(acc30[j] + b2a, s2a, t2a), 0.0f);
            float h1 = fmaxf(fmaf(acc31[j] + b2b, s2b, t2b), 0.0f);
            float lp = h0 * w3a + h1 * w3b;
#pragma unroll
            for (int d = 32; d; d >>= 1) lp += __shfl_xor(lp, d, 64);
            float sc = 1.0f / (1.0f + expf(-(lp + b3v)));
            if (lane == j) scores[(size_t)b * EE + T0 + ebase + j] = sc;
        }
    }
}

// ---------------- parallel radix-select: histogram pass ----------------
__global__ void k_hist(const float* __restrict__ scores, const unsigned* __restrict__ selp,
                       unsigned* __restrict__ ghist, int pass) {
    __shared__ unsigned h[256];
    int b = blockIdx.y;
    h[threadIdx.x] = 0u;
    __syncthreads();
    unsigned pref = selp[b];
    unsigned mask = (pass == 3) ? 0u : (0xFFFFFFFFu << ((pass + 1) * 8));
    const unsigned* sb = (const unsigned*)(scores + (size_t)b * EE);
    int base = blockIdx.x * 2048;
    for (int i = base + threadIdx.x; i < base + 2048; i += 256) {
        unsigned u = sb[i];
        if ((u & mask) == pref) atomicAdd(&h[(u >> (pass * 8)) & 255], 1u);
    }
    __syncthreads();
    unsigned v = h[threadIdx.x];
    if (v) atomicAdd(&ghist[b * 256 + threadIdx.x], v);
}

// ---------------- parallel radix-select: pick digit, reset hist ----------------
__global__ void k_pick(unsigned* __restrict__ ghist, unsigned* __restrict__ selp,
                       int* __restrict__ selr, float* __restrict__ thr, int pass) {
    __shared__ unsigned sh[256];
    int b = blockIdx.x;
    unsigned* gh = ghist + b * 256;
    sh[threadIdx.x] = gh[threadIdx.x];
    __syncthreads();
    if (threadIdx.x == 0) {
        unsigned r = (unsigned)selr[b], cum = 0;
        for (int x = 0; x < 256; ++x) {
            unsigned c = sh[x];
            if (cum + c > r) {
                selp[b] |= (unsigned)x << (pass * 8);
                selr[b] = (int)(r - cum);
                break;
            }
            cum += c;
        }
        if (pass == 0) thr[b] = __uint_as_float(selp[b]);
    }
    __syncthreads();
    gh[threadIdx.x] = 0u;
}

// ---------------- threshold + per-group repair + scatter ----------------
__global__ void k_scatter(const float* __restrict__ scores, const float* __restrict__ thr,
                          const int* __restrict__ src, const int* __restrict__ tgt,
                          const int* __restrict__ mep, float* __restrict__ out) {
    int gid = blockIdx.x * 256 + threadIdx.x;
    int b = gid >> 16;
    int lane = threadIdx.x & 63;
    int j = lane & 15;
    float s = scores[gid];
    float t = thr[b];
    bool above = (s >= t);
    unsigned long long bal = __ballot(above);
    int sub = lane >> 4;
    unsigned int mask16 = (unsigned int)((bal >> (sub * 16)) & 0xFFFFull);
    int active = __popc(mask16);
    int rank = 0;
#pragma unroll
    for (int j2 = 0; j2 < 16; ++j2) {
        float sv = __shfl(s, (lane & 48) + j2, 64);
        rank += (sv > s || (sv == s && j2 < j)) ? 1 : 0;
    }
    int me = *mep;
    int need = (active < me) ? min(me - active, DEGQ) : 0;
    bool keep = above || (rank < need);
    float wgt = keep ? s : 0.0f;
    out[(size_t)b * NN * NN + (size_t)src[gid] * NN + tgt[gid]] = wgt;
}

extern "C" void kernel_launch(void* const* d_in, const int* in_sizes, int n_in,
                              void* d_out, int out_size, void* d_ws, size_t ws_size,
                              hipStream_t stream) {
    const float* nf  = (const float*)d_in[0];
    const int*   src = (const int*)d_in[1];
    const int*   tgt = (const int*)d_in[2];
    const float* Wa1 = (const float*)d_in[3];
    const float* ba1 = (const float*)d_in[4];
    const float* Wa2 = (const float*)d_in[5];
    const float* ba2 = (const float*)d_in[6];
    const float* W1  = (const float*)d_in[7];
    const float* b1  = (const float*)d_in[8];
    const float* g1  = (const float*)d_in[9];
    const float* be1 = (const float*)d_in[10];
    const float* m1  = (const float*)d_in[11];
    const float* v1  = (const float*)d_in[12];
    const float* W2  = (const float*)d_in[13];
    const float* b2  = (const float*)d_in[14];
    const float* g2  = (const float*)d_in[15];
    const float* be2 = (const float*)d_in[16];
    const float* m2  = (const float*)d_in[17];
    const float* v2  = (const float*)d_in[18];
    const float* W3  = (const float*)d_in[19];
    const float* b3  = (const float*)d_in[20];
    const int*   mep = (const int*)d_in[21];

    float* ws = (float*)d_ws;
    float*    xn     = ws + WS_XN;
    float*    uvpq   = ws + WS_UVPQ;
    float*    scores = ws + WS_SCORES;
    float*    thrb   = ws + WS_THR;
    unsigned* selp   = (unsigned*)(ws + WS_SELP);
    int*      selr   = (int*)(ws + WS_SELR);
    unsigned* ghist  = (unsigned*)(ws + WS_GHIST);
    float*    bn     = ws + WS_BN;
    float*    out    = (float*)d_out;

    hipMemsetAsync(d_out, 0, (size_t)out_size * sizeof(float), stream);
    k_prep<<<1, 256, 0, stream>>>(g1, be1, m1, v1, g2, be2, m2, v2, bn, ghist, selp, selr);
    k_norm<<<(BB * NN) / 4, 256, 0, stream>>>(nf, xn);
    k_uvpq<<<dim3((BB * NN) / 32, 6), 256, 0, stream>>>(xn, Wa1, W1, uvpq);
    k_edge<<<dim3(EE / 64, BB), 512, 0, stream>>>(xn, uvpq, Wa2, ba1, ba2, W1, b1,
                                                  W2, b2, W3, b3, src, tgt, bn, scores);
    for (int pass = 3; pass >= 0; --pass) {
        k_hist<<<dim3(32, BB), 256, 0, stream>>>(scores, selp, ghist, pass);
        k_pick<<<BB, 256, 0, stream>>>(ghist, selp, selr, thrb, pass);
    }
    k_scatter<<<(BB * EE) / 256, 256, 0, stream>>>(scores, thrb, src, tgt, mep, out);
}